// Round 8
// baseline (427.940 us; speedup 1.0000x reference)
//
#include <hip/hip_runtime.h>
#include <stdint.h>

typedef __bf16 bf16;
typedef __bf16 bf16x8 __attribute__((ext_vector_type(8)));
typedef __bf16 bf16x4 __attribute__((ext_vector_type(4)));
typedef float f32x4 __attribute__((ext_vector_type(4)));

#define DEVFN static __device__ __forceinline__

constexpr int S = 2048, Hdim = 2048, NH = 16, NKV = 4, HD = 128, RHD = 64, QC = 1536, KVC = 512;
constexpr int QKD = HD + RHD;                 // 192
constexpr int DN = 2112;                      // merged down-proj width: QC + KVC + RHD
constexpr float RMS_EPS = 1e-6f;
constexpr float ATT_SCALE = 0.07216878364870323f;  // 1/sqrt(192)

// ---------------- reductions ----------------
DEVFN float wave_sum(float v) {
#pragma unroll
  for (int o = 32; o > 0; o >>= 1) v += __shfl_xor(v, o, 64);
  return v;
}
DEVFN float block_sum(float v) {
  __shared__ float red_s[4];
  v = wave_sum(v);
  int lane = threadIdx.x & 63, wid = threadIdx.x >> 6;
  if (lane == 0) red_s[wid] = v;
  __syncthreads();
  v = red_s[0] + red_s[1] + red_s[2] + red_s[3];
  __syncthreads();
  return v;
}

// ---------------- async global->LDS (16B per lane) ----------------
DEVFN void gload16(const bf16* g, bf16* l) {
  __builtin_amdgcn_global_load_lds(
      (const __attribute__((address_space(1))) uint32_t*)g,
      (__attribute__((address_space(3))) uint32_t*)l, 16, 0, 0);
}

// ---------------- async GEMM core (m97 structure): C = A[M,K] * Bt[N,K]^T ---
template <typename OT>
DEVFN void gemm_core_async(const bf16* __restrict__ A, const bf16* __restrict__ Bt,
                           OT* __restrict__ C, int N, int lda, int ldb, int ldc,
                           int m0, int n0, float scale, int kend) {
  __shared__ alignas(16) bf16 As[128 * 32];
  __shared__ alignas(16) bf16 Bs[128 * 32];
  const int t = threadIdx.x;
  const int lane = t & 63;
  const int wm = ((t >> 7) & 1) * 64;
  const int wn = ((t >> 6) & 1) * 64;
  const int lr = lane & 15;
  const int lk = (lane >> 4) * 8;
  const int srow = t >> 2;
  const int scol = (t & 3) * 8;
  const bf16* Ab = A + (size_t)(m0 + srow) * lda + scol;
  const bf16* Bb = Bt + (size_t)(n0 + srow) * ldb + scol;
  bf16* Al = As + t * 8;
  bf16* Bl = Bs + t * 8;

  f32x4 acc[4][4];
#pragma unroll
  for (int i = 0; i < 4; i++)
#pragma unroll
    for (int j = 0; j < 4; j++) { f32x4 z = {0.f, 0.f, 0.f, 0.f}; acc[i][j] = z; }

  for (int kk = 0; kk < kend; kk += 32) {
    gload16(Ab + kk, Al);
    gload16(Ab + (size_t)64 * lda + kk, Al + 2048);
    gload16(Bb + kk, Bl);
    gload16(Bb + (size_t)64 * ldb + kk, Bl + 2048);
    __syncthreads();
    bf16x8 a[4], b[4];
#pragma unroll
    for (int i = 0; i < 4; i++)
      a[i] = *reinterpret_cast<const bf16x8*>(&As[(wm + i * 16 + lr) * 32 + lk]);
#pragma unroll
    for (int i = 0; i < 4; i++)
      b[i] = *reinterpret_cast<const bf16x8*>(&Bs[(wn + i * 16 + lr) * 32 + lk]);
#pragma unroll
    for (int i = 0; i < 4; i++)
#pragma unroll
      for (int j = 0; j < 4; j++)
        acc[i][j] = __builtin_amdgcn_mfma_f32_16x16x32_bf16(a[i], b[j], acc[i][j], 0, 0, 0);
    __syncthreads();
  }
  const int orow = (lane >> 4) * 4;
#pragma unroll
  for (int i = 0; i < 4; i++) {
#pragma unroll
    for (int j = 0; j < 4; j++) {
      int col = n0 + wn + j * 16 + lr;
      if (col < N) {
#pragma unroll
        for (int q = 0; q < 4; q++) {
          int row = m0 + wm + i * 16 + orow + q;
          C[(size_t)row * ldc + col] = (OT)(acc[i][j][q] * scale);
        }
      }
    }
  }
}

template <typename OT>
__global__ __launch_bounds__(256) void gemm_nt(const bf16* __restrict__ A, const bf16* __restrict__ Bt,
                                               OT* __restrict__ C, int N, int K, int lda,
                                               int ldb, int ldc, float scale) {
  gemm_core_async<OT>(A, Bt, C, N, lda, ldb, ldc, blockIdx.y * 128, blockIdx.x * 128, scale, K);
}

// raw causal scores, all heads in one launch; writes only n0<=m0 blocks
__global__ __launch_bounds__(256) void gemm_scores(const bf16* __restrict__ qpack,
                                                   const bf16* __restrict__ kpack,
                                                   float* __restrict__ attn) {
  int h = blockIdx.z;
  int g = h >> 2;
  int m0 = blockIdx.y * 128, n0 = blockIdx.x * 128;
  if (n0 > m0) return;
  gemm_core_async<float>(qpack + (size_t)h * S * QKD, kpack + (size_t)g * S * QKD,
                         attn + (size_t)h * S * S, S, QKD, QKD, S, m0, n0, ATT_SCALE, QKD);
}

// ---------------- per-row softmax stats (m, 1/l), one wave per row ----------
__global__ __launch_bounds__(256) void attn_stats(const float* __restrict__ attn,
                                                  float* __restrict__ stats) {
  const int h = blockIdx.y;
  const int wid = threadIdx.x >> 6, lane = threadIdx.x & 63;
  const int s = blockIdx.x * 4 + wid;
  const float* row = attn + ((size_t)h * S + s) * S;
  const int n = s + 1;
  float m = -1e30f, l = 0.f;
  for (int c = lane * 4; c < n; c += 256) {
    float4 v = *reinterpret_cast<const float4*>(row + c);
    float e[4] = {v.x, v.y, v.z, v.w};
    float cm = -1e30f;
#pragma unroll
    for (int u = 0; u < 4; u++) cm = fmaxf(cm, (c + u <= s) ? e[u] : -1e30f);
    float nm = fmaxf(m, cm);
    float ss = 0.f;
#pragma unroll
    for (int u = 0; u < 4; u++) ss += (c + u <= s) ? __expf(e[u] - nm) : 0.f;
    l = l * __expf(m - nm) + ss;
    m = nm;
  }
#pragma unroll
  for (int o = 1; o < 64; o <<= 1) {
    float mo = __shfl_xor(m, o, 64);
    float lo = __shfl_xor(l, o, 64);
    float M = fmaxf(m, mo);
    l = l * __expf(m - M) + lo * __expf(mo - M);
    m = M;
  }
  if (lane == 0) {
    stats[((size_t)h * S + s) * 2] = m;
    stats[((size_t)h * S + s) * 2 + 1] = 1.0f / l;
  }
}

// ---------------- fused normalize + attn write + PV (v3) ----------------
// Block = two 16-row balanced strips of one head. Per 128-col step:
// {B-frags direct from global (L2-hot V, issued FIRST so counted vmcnt never
// drains the attn stores), normalize+write fp32 attn, bf16 P -> double-buffered
// As (4.3KB x2), ONE lgkm-only barrier, 8 MFMA/wave}. 4 waves x 32 out cols.
__global__ __launch_bounds__(256) void smpv(float* __restrict__ attn,
                                            const float* __restrict__ stats,
                                            const bf16* __restrict__ vt,
                                            bf16* __restrict__ ctxb) {
  const int h = blockIdx.y;
  float* Ah = attn + (size_t)h * S * S;
  const bf16* Bt = vt + (size_t)(h >> 2) * HD * S;
  bf16* C = ctxb + h * HD;

  __shared__ alignas(16) bf16 As[2][16 * 136];

  const int t = threadIdx.x;
  const int lane = t & 63;
  const int wid = t >> 6;
  const int r0 = t >> 4;         // staging row 0..15
  const int c0 = (t & 15) * 8;   // staging col 0..120
  const int wn = wid * 32;       // wave's output-col base
  const int lr = lane & 15;
  const int lk = (lane >> 4) * 8;
  const bf16* Bb0 = Bt + (size_t)(wn + lr) * S + lk;        // j=0 frag base
  const bf16* Bb1 = Bt + (size_t)(wn + 16 + lr) * S + lk;   // j=1 frag base

  for (int sub = 0; sub < 2; ++sub) {
    const int m0 = sub ? (2032 - 16 * blockIdx.x) : (16 * blockIdx.x);
    const int kend = m0 + 16;                 // rows [m0,m0+16) need k <= m0+15
    const int kup = (kend + 127) & ~127;      // round up to 128-block
    const int rowg = m0 + r0;
    float* Arow = Ah + (size_t)rowg * S;
    const float mr = stats[((size_t)h * S + rowg) * 2];
    const float invl = stats[((size_t)h * S + rowg) * 2 + 1];

    f32x4 acc[2];
#pragma unroll
    for (int j = 0; j < 2; j++) { f32x4 z = {0.f, 0.f, 0.f, 0.f}; acc[j] = z; }

    int buf = 0;
    for (int kk = 0; kk < kup; kk += 128, buf ^= 1) {
      // B-fragments straight from global (V is L2-resident) — issued first
      bf16x8 b0_0 = *reinterpret_cast<const bf16x8*>(Bb0 + kk);
      bf16x8 b0_1 = *reinterpret_cast<const bf16x8*>(Bb0 + kk + 32);
      bf16x8 b0_2 = *reinterpret_cast<const bf16x8*>(Bb0 + kk + 64);
      bf16x8 b0_3 = *reinterpret_cast<const bf16x8*>(Bb0 + kk + 96);
      bf16x8 b1_0 = *reinterpret_cast<const bf16x8*>(Bb1 + kk);
      bf16x8 b1_1 = *reinterpret_cast<const bf16x8*>(Bb1 + kk + 32);
      bf16x8 b1_2 = *reinterpret_cast<const bf16x8*>(Bb1 + kk + 64);
      bf16x8 b1_3 = *reinterpret_cast<const bf16x8*>(Bb1 + kk + 96);
      // normalize raw scores, write back fp32, stash bf16 P in LDS
      {
        float* p = Arow + kk + c0;
        float4 f0 = *reinterpret_cast<const float4*>(p);
        float4 f1 = *reinterpret_cast<const float4*>(p + 4);
        float v[8] = {f0.x, f0.y, f0.z, f0.w, f1.x, f1.y, f1.z, f1.w};
        bf16x8 vb;
#pragma unroll
        for (int e = 0; e < 8; e++) {
          float pe = (kk + c0 + e <= rowg) ? __expf(v[e] - mr) * invl : 0.f;
          v[e] = pe;
          vb[e] = (bf16)pe;
        }
        *reinterpret_cast<float4*>(p) = make_float4(v[0], v[1], v[2], v[3]);
        *reinterpret_cast<float4*>(p + 4) = make_float4(v[4], v[5], v[6], v[7]);
        *reinterpret_cast<bf16x8*>(&As[buf][r0 * 136 + c0]) = vb;
      }
      asm volatile("s_waitcnt lgkmcnt(0)" ::: "memory");
      __builtin_amdgcn_s_barrier();
      bf16x8 a0 = *reinterpret_cast<const bf16x8*>(&As[buf][lr * 136 + lk]);
      bf16x8 a1 = *reinterpret_cast<const bf16x8*>(&As[buf][lr * 136 + 32 + lk]);
      bf16x8 a2 = *reinterpret_cast<const bf16x8*>(&As[buf][lr * 136 + 64 + lk]);
      bf16x8 a3 = *reinterpret_cast<const bf16x8*>(&As[buf][lr * 136 + 96 + lk]);
      acc[0] = __builtin_amdgcn_mfma_f32_16x16x32_bf16(a0, b0_0, acc[0], 0, 0, 0);
      acc[0] = __builtin_amdgcn_mfma_f32_16x16x32_bf16(a1, b0_1, acc[0], 0, 0, 0);
      acc[0] = __builtin_amdgcn_mfma_f32_16x16x32_bf16(a2, b0_2, acc[0], 0, 0, 0);
      acc[0] = __builtin_amdgcn_mfma_f32_16x16x32_bf16(a3, b0_3, acc[0], 0, 0, 0);
      acc[1] = __builtin_amdgcn_mfma_f32_16x16x32_bf16(a0, b1_0, acc[1], 0, 0, 0);
      acc[1] = __builtin_amdgcn_mfma_f32_16x16x32_bf16(a1, b1_1, acc[1], 0, 0, 0);
      acc[1] = __builtin_amdgcn_mfma_f32_16x16x32_bf16(a2, b1_2, acc[1], 0, 0, 0);
      acc[1] = __builtin_amdgcn_mfma_f32_16x16x32_bf16(a3, b1_3, acc[1], 0, 0, 0);
    }

    // zero-fill causal tail [kup, S)
    const float4 zz = make_float4(0.f, 0.f, 0.f, 0.f);
    for (int kk = kup; kk < S; kk += 128) {
      float* p = Arow + kk + c0;
      *reinterpret_cast<float4*>(p) = zz;
      *reinterpret_cast<float4*>(p + 4) = zz;
    }

    // epilogue: ctx write (16 rows x 128 cols)
    const int orow = (lane >> 4) * 4;
#pragma unroll
    for (int j = 0; j < 2; j++) {
      int col = wn + j * 16 + lr;
#pragma unroll
      for (int q = 0; q < 4; q++) {
        int row = m0 + orow + q;
        C[(size_t)row * Hdim + col] = (bf16)acc[j][q];
      }
    }
    __syncthreads();  // recycle As buffers across sub-strips
  }
}

// ---------------- elementwise / reshape ----------------
__global__ __launch_bounds__(256) void cast_f32_bf16(const float* __restrict__ in,
                                                     bf16* __restrict__ out, int n8) {
  int i = blockIdx.x * 256 + threadIdx.x;
  if (i >= n8) return;
  float4 f0 = *reinterpret_cast<const float4*>(in + (size_t)i * 8);
  float4 f1 = *reinterpret_cast<const float4*>(in + (size_t)i * 8 + 4);
  bf16x8 v;
  v[0] = (bf16)f0.x; v[1] = (bf16)f0.y; v[2] = (bf16)f0.z; v[3] = (bf16)f0.w;
  v[4] = (bf16)f1.x; v[5] = (bf16)f1.y; v[6] = (bf16)f1.z; v[7] = (bf16)f1.w;
  *reinterpret_cast<bf16x8*>(out + (size_t)i * 8) = v;
}

// batched fp32 [R][C] -> bf16 [C][R] transposes (8 jobs, one dispatch)
struct TJobs {
  const float* src[8];
  bf16* dst[8];
  int R[8], C[8], tiles[8];
};

__global__ __launch_bounds__(256) void transpose_batch(TJobs J) {
  int tile = blockIdx.x;
  int j = 0;
  while (tile >= J.tiles[j]) { tile -= J.tiles[j]; ++j; }
  const int C = J.C[j], R = J.R[j];
  int tcn = C >> 5;
  int rb = (tile / tcn) * 32, cb = (tile % tcn) * 32;
  const float* in = J.src[j];
  bf16* out = J.dst[j];
  __shared__ float tl[32][33];
  int tx = threadIdx.x, ty = threadIdx.y;
#pragma unroll
  for (int q = 0; q < 32; q += 8)
    tl[ty + q][tx] = in[(size_t)(rb + ty + q) * C + cb + tx];
  __syncthreads();
#pragma unroll
  for (int q = 0; q < 32; q += 8)
    out[(size_t)(cb + ty + q) * R + rb + tx] = (bf16)tl[tx][ty + q];
}

// bf16 [R][C] (ld=ild) -> bf16 [C][R] (ld=old_)
__global__ __launch_bounds__(256) void transpose_b16(const bf16* __restrict__ in,
                                                     bf16* __restrict__ out, int R, int ild, int old_) {
  __shared__ float tl[32][33];
  int tx = threadIdx.x, ty = threadIdx.y;
  int cb = blockIdx.x * 32, rb = blockIdx.y * 32;
#pragma unroll
  for (int q = 0; q < 32; q += 8)
    tl[ty + q][tx] = (float)in[(size_t)(rb + ty + q) * ild + cb + tx];
  __syncthreads();
#pragma unroll
  for (int q = 0; q < 32; q += 8)
    out[(size_t)(cb + ty + q) * old_ + rb + tx] = (bf16)tl[tx][ty + q];
}

// fused RMSNorm for cq (y==0) and ckv (y==1) reading merged dproj
__global__ __launch_bounds__(256) void rmsnorm_fused(const float* __restrict__ dproj,
                                                     const float* __restrict__ qw,
                                                     const float* __restrict__ kw,
                                                     bf16* __restrict__ cqb,
                                                     bf16* __restrict__ ckvb) {
  int row = blockIdx.x;
  bool isq = (blockIdx.y == 0);
  int C = isq ? QC : KVC;
  const float* p = dproj + (size_t)row * DN + (isq ? 0 : QC);
  const float* w = isq ? qw : kw;
  bf16* out = (isq ? cqb : ckvb) + (size_t)row * C;
  float ss = 0.f;
  for (int i = threadIdx.x * 4; i < C; i += 1024) {
    float4 v = *reinterpret_cast<const float4*>(p + i);
    ss += v.x * v.x + v.y * v.y + v.z * v.z + v.w * v.w;
  }
  ss = block_sum(ss);
  float r = rsqrtf(ss / (float)C + RMS_EPS);
  for (int i = threadIdx.x * 4; i < C; i += 1024) {
    float4 v = *reinterpret_cast<const float4*>(p + i);
    float4 g = *reinterpret_cast<const float4*>(w + i);
    bf16x4 o;
    o[0] = (bf16)(v.x * r * g.x); o[1] = (bf16)(v.y * r * g.y);
    o[2] = (bf16)(v.z * r * g.z); o[3] = (bf16)(v.w * r * g.w);
    *reinterpret_cast<bf16x4*>(out + i) = o;
  }
}

// fused: pack qc slice of up1 into qpack + RoPE'd qr into qpack[...,128:]
__global__ __launch_bounds__(256) void build_qpack(const bf16* __restrict__ up1,
                                                   const float* __restrict__ cosp,
                                                   const float* __restrict__ sinp,
                                                   bf16* __restrict__ qpack) {
  int idx = blockIdx.x * 256 + threadIdx.x;
  const int P = NH * S * 16;  // 8-elem chunks of qc
  if (idx < P) {
    int d8 = idx & 15, s = (idx >> 4) & (S - 1), h = idx >> 15;
    int4 v = *reinterpret_cast<const int4*>(up1 + (size_t)s * 3072 + h * HD + d8 * 8);
    *reinterpret_cast<int4*>(qpack + ((size_t)h * S + s) * QKD + d8 * 8) = v;
  } else {
    int j = idx - P;
    int d0 = (j & 7) * 8, s = (j >> 3) & (S - 1), h = j >> 14;
    const bf16* xr = up1 + (size_t)s * 3072 + 2048 + h * RHD;
    bf16x8 xa = *reinterpret_cast<const bf16x8*>(xr + d0);
    bf16x8 xb = *reinterpret_cast<const bf16x8*>(xr + (d0 ^ 32));
    float sign = (d0 < 32) ? -1.f : 1.f;
    const float* cr = cosp + s * RHD + d0;
    const float* sr = sinp + s * RHD + d0;
    bf16x8 o;
#pragma unroll
    for (int i = 0; i < 8; i++)
      o[i] = (bf16)((float)xa[i] * cr[i] + sign * (float)xb[i] * sr[i]);
    *reinterpret_cast<bf16x8*>(qpack + ((size_t)h * S + s) * QKD + HD + d0) = o;
  }
}

// fused: pack kc slice of up2 into kpack + RoPE'd kr (from dproj col 2048) into all groups
__global__ __launch_bounds__(256) void build_kpack(const bf16* __restrict__ up2,
                                                   const float* __restrict__ dproj,
                                                   const float* __restrict__ cosp,
                                                   const float* __restrict__ sinp,
                                                   bf16* __restrict__ kpack) {
  int idx = blockIdx.x * 256 + threadIdx.x;
  const int P = NKV * S * 16;
  if (idx < P) {
    int d8 = idx & 15, s = (idx >> 4) & (S - 1), g = idx >> 15;
    int4 v = *reinterpret_cast<const int4*>(up2 + (size_t)s * 1024 + g * HD + d8 * 8);
    *reinterpret_cast<int4*>(kpack + ((size_t)g * S + s) * QKD + d8 * 8) = v;
  } else {
    int j = idx - P;
    int d0 = (j & 7) * 8, s = j >> 3;
    const float* xr = dproj + (size_t)s * DN + 2048;
    float4 a0 = *reinterpret_cast<const float4*>(xr + d0);
    float4 a1 = *reinterpret_cast<const float4*>(xr + d0 + 4);
    float4 b0 = *reinterpret_cast<const float4*>(xr + (d0 ^ 32));
    float4 b1 = *reinterpret_cast<const float4*>(xr + (d0 ^ 32) + 4);
    float sign = (d0 < 32) ? -1.f : 1.f;
    const float* cr = cosp + s * RHD + d0;
    const float* sr = sinp + s * RHD + d0;
    float xa[8] = {a0.x, a0.y, a0.z, a0.w, a1.x, a1.y, a1.z, a1.w};
    float xb[8] = {b0.x, b0.y, b0.z, b0.w, b1.x, b1.y, b1.z, b1.w};
    bf16x8 o;
#pragma unroll
    for (int i = 0; i < 8; i++)
      o[i] = (bf16)(xa[i] * cr[i] + sign * xb[i] * sr[i]);
#pragma unroll
    for (int g = 0; g < NKV; g++)
      *reinterpret_cast<bf16x8*>(kpack + ((size_t)g * S + s) * QKD + HD + d0) = o;
  }
}

// ---------------- launcher ----------------
extern "C" void kernel_launch(void* const* d_in, const int* in_sizes, int n_in, void* d_out,
                              int out_size, void* d_ws, size_t ws_size, hipStream_t stream) {
  const float* Xf = (const float*)d_in[0];
  const float* cosp = (const float*)d_in[1];
  const float* sinp = (const float*)d_in[2];
  const float* w_down_q = (const float*)d_in[4];
  const float* w_up_q = (const float*)d_in[5];
  const float* w_qr = (const float*)d_in[6];
  const float* w_down_kv = (const float*)d_in[7];
  const float* w_up_k = (const float*)d_in[8];
  const float* w_up_v = (const float*)d_in[9];
  const float* w_kr = (const float*)d_in[10];
  const float* w_o = (const float*)d_in[11];
  const float* q_norm_w = (const float*)d_in[12];
  const float* k_norm_w = (const float*)d_in[13];

  float* out0 = (float*)d_out;
  float* attn = out0 + (size_t)S * Hdim;

  char* base = (char*)d_ws;
  size_t off = 0;
  auto carve = [&](size_t bytes) -> void* {
    void* p = base + off;
    off += (bytes + 255) & ~(size_t)255;
    return p;
  };
  bf16* Xb      = (bf16*)carve((size_t)S * Hdim * 2);
  bf16* wt_down = (bf16*)carve((size_t)2176 * 2048 * 2);  // [2112(+pad)][2048]
  bf16* wt_up1  = (bf16*)carve((size_t)3072 * QC * 2);    // [3072][1536]
  bf16* wt_up2  = (bf16*)carve((size_t)1024 * KVC * 2);   // [1024][512]
  bf16* wt_o    = (bf16*)carve((size_t)Hdim * Hdim * 2);
  float* dproj  = (float*)carve((size_t)S * DN * 4);      // [2048][2112]
  bf16* cqb     = (bf16*)carve((size_t)S * QC * 2);
  bf16* ckvb    = (bf16*)carve((size_t)S * KVC * 2);
  bf16* up1     = (bf16*)carve((size_t)S * 3072 * 2);     // [s][qc 0:2048 | qr 2048:3072]
  bf16* up2     = (bf16*)carve((size_t)S * 1024 * 2);     // [s][kc 0:512 | v 512:1024]
  bf16* qpack   = (bf16*)carve((size_t)NH * S * QKD * 2);
  bf16* kpack   = (bf16*)carve((size_t)NKV * S * QKD * 2);
  bf16* vt      = (bf16*)carve((size_t)NKV * HD * S * 2);
  bf16* ctxb    = (bf16*)carve((size_t)S * Hdim * 2);
  float* stats  = (float*)carve((size_t)NH * S * 2 * 4);  // per-row (m, 1/l)
  (void)in_sizes; (void)n_in; (void)out_size; (void)ws_size;

  dim3 tb(32, 8);
  cast_f32_bf16<<<S * Hdim / 8 / 256, 256, 0, stream>>>(Xf, Xb, S * Hdim / 8);

  TJobs J;
  const float* srcs[8] = {w_down_q, w_down_kv, w_kr, w_up_q, w_qr, w_up_k, w_up_v, w_o};
  bf16* dsts[8] = {wt_down, wt_down + (size_t)QC * 2048, wt_down + (size_t)2048 * 2048,
                   wt_up1, wt_up1 + (size_t)2048 * QC, wt_up2, wt_up2 + (size_t)512 * KVC, wt_o};
  int Rs[8] = {2048, 2048, 2048, 1536, 1536, 512, 512, 2048};
  int Cs[8] = {1536, 512, 64, 2048, 1024, 512, 512, 2048};
  int total_tiles = 0;
  for (int j = 0; j < 8; j++) {
    J.src[j] = srcs[j]; J.dst[j] = dsts[j]; J.R[j] = Rs[j]; J.C[j] = Cs[j];
    J.tiles[j] = (Rs[j] / 32) * (Cs[j] / 32);
    total_tiles += J.tiles[j];
  }
  transpose_batch<<<total_tiles, tb, 0, stream>>>(J);

  // merged down projection: [S][2112] = Xb @ [wdq | wdkv | wkr]
  gemm_nt<float><<<dim3(17, 16), 256, 0, stream>>>(Xb, wt_down, dproj, DN, Hdim, Hdim, Hdim, DN, 1.f);
  rmsnorm_fused<<<dim3(S, 2), 256, 0, stream>>>(dproj, q_norm_w, k_norm_w, cqb, ckvb);

  // merged up projections
  gemm_nt<bf16><<<dim3(24, 16), 256, 0, stream>>>(cqb, wt_up1, up1, 3072, QC, QC, QC, 3072, 1.f);
  gemm_nt<bf16><<<dim3(8, 16), 256, 0, stream>>>(ckvb, wt_up2, up2, 1024, KVC, KVC, KVC, 1024, 1.f);

  build_qpack<<<(NH * S * 16 + NH * S * 8) / 256, 256, 0, stream>>>(up1, cosp, sinp, qpack);
  build_kpack<<<(NKV * S * 16 + S * 8) / 256, 256, 0, stream>>>(up2, dproj, cosp, sinp, kpack);
  transpose_b16<<<dim3(512 / 32, S / 32), tb, 0, stream>>>(up2 + 512, vt, S, 1024, S);

  // raw scores (all heads, one launch)
  gemm_scores<<<dim3(16, 16, NH), 256, 0, stream>>>(qpack, kpack, attn);
  // per-row softmax stats (one wave per row, fully parallel)
  attn_stats<<<dim3(S / 4, NH), 256, 0, stream>>>(attn, stats);
  // fused normalize + attn write + PV (v3: direct-global V, 1 barrier/step)
  smpv<<<dim3(64, NH), 256, 0, stream>>>(attn, stats, vt, ctxb);
  // output projection
  gemm_nt<float><<<dim3(16, 16), 256, 0, stream>>>(ctxb, wt_o, out0, Hdim, Hdim, Hdim, Hdim, Hdim, 1.f);
}

// Round 9
// 395.923 us; speedup vs baseline: 1.0809x; 1.0809x over previous
//
#include <hip/hip_runtime.h>
#include <stdint.h>

typedef __bf16 bf16;
typedef __bf16 bf16x8 __attribute__((ext_vector_type(8)));
typedef __bf16 bf16x4 __attribute__((ext_vector_type(4)));
typedef float f32x4 __attribute__((ext_vector_type(4)));

#define DEVFN static __device__ __forceinline__

constexpr int S = 2048, Hdim = 2048, NH = 16, NKV = 4, HD = 128, RHD = 64, QC = 1536, KVC = 512;
constexpr int QKD = HD + RHD;                 // 192
constexpr int DN = 2112;                      // merged down-proj width: QC + KVC + RHD
constexpr float RMS_EPS = 1e-6f;
constexpr float ATT_SCALE = 0.07216878364870323f;  // 1/sqrt(192)

// ---------------- reductions ----------------
DEVFN float wave_sum(float v) {
#pragma unroll
  for (int o = 32; o > 0; o >>= 1) v += __shfl_xor(v, o, 64);
  return v;
}
DEVFN float block_sum(float v) {
  __shared__ float red_s[4];
  v = wave_sum(v);
  int lane = threadIdx.x & 63, wid = threadIdx.x >> 6;
  if (lane == 0) red_s[wid] = v;
  __syncthreads();
  v = red_s[0] + red_s[1] + red_s[2] + red_s[3];
  __syncthreads();
  return v;
}

DEVFN void lgkm_barrier() {
  asm volatile("s_waitcnt lgkmcnt(0)" ::: "memory");
  __builtin_amdgcn_s_barrier();
}

// ---------------- async global->LDS (16B per lane) ----------------
DEVFN void gload16(const bf16* g, bf16* l) {
  __builtin_amdgcn_global_load_lds(
      (const __attribute__((address_space(1))) uint32_t*)g,
      (__attribute__((address_space(3))) uint32_t*)l, 16, 0, 0);
}

// ---------------- async GEMM core (m97 structure): C = A[M,K] * Bt[N,K]^T ---
template <typename OT>
DEVFN void gemm_core_async(const bf16* __restrict__ A, const bf16* __restrict__ Bt,
                           OT* __restrict__ C, int N, int lda, int ldb, int ldc,
                           int m0, int n0, float scale, int kend) {
  __shared__ alignas(16) bf16 As[128 * 32];
  __shared__ alignas(16) bf16 Bs[128 * 32];
  const int t = threadIdx.x;
  const int lane = t & 63;
  const int wm = ((t >> 7) & 1) * 64;
  const int wn = ((t >> 6) & 1) * 64;
  const int lr = lane & 15;
  const int lk = (lane >> 4) * 8;
  const int srow = t >> 2;
  const int scol = (t & 3) * 8;
  const bf16* Ab = A + (size_t)(m0 + srow) * lda + scol;
  const bf16* Bb = Bt + (size_t)(n0 + srow) * ldb + scol;
  bf16* Al = As + t * 8;
  bf16* Bl = Bs + t * 8;

  f32x4 acc[4][4];
#pragma unroll
  for (int i = 0; i < 4; i++)
#pragma unroll
    for (int j = 0; j < 4; j++) { f32x4 z = {0.f, 0.f, 0.f, 0.f}; acc[i][j] = z; }

  for (int kk = 0; kk < kend; kk += 32) {
    gload16(Ab + kk, Al);
    gload16(Ab + (size_t)64 * lda + kk, Al + 2048);
    gload16(Bb + kk, Bl);
    gload16(Bb + (size_t)64 * ldb + kk, Bl + 2048);
    __syncthreads();
    bf16x8 a[4], b[4];
#pragma unroll
    for (int i = 0; i < 4; i++)
      a[i] = *reinterpret_cast<const bf16x8*>(&As[(wm + i * 16 + lr) * 32 + lk]);
#pragma unroll
    for (int i = 0; i < 4; i++)
      b[i] = *reinterpret_cast<const bf16x8*>(&Bs[(wn + i * 16 + lr) * 32 + lk]);
#pragma unroll
    for (int i = 0; i < 4; i++)
#pragma unroll
      for (int j = 0; j < 4; j++)
        acc[i][j] = __builtin_amdgcn_mfma_f32_16x16x32_bf16(a[i], b[j], acc[i][j], 0, 0, 0);
    __syncthreads();
  }
  const int orow = (lane >> 4) * 4;
#pragma unroll
  for (int i = 0; i < 4; i++) {
#pragma unroll
    for (int j = 0; j < 4; j++) {
      int col = n0 + wn + j * 16 + lr;
      if (col < N) {
#pragma unroll
        for (int q = 0; q < 4; q++) {
          int row = m0 + wm + i * 16 + orow + q;
          C[(size_t)row * ldc + col] = (OT)(acc[i][j][q] * scale);
        }
      }
    }
  }
}

template <typename OT>
__global__ __launch_bounds__(256) void gemm_nt(const bf16* __restrict__ A, const bf16* __restrict__ Bt,
                                               OT* __restrict__ C, int N, int K, int lda,
                                               int ldb, int ldc, float scale) {
  gemm_core_async<OT>(A, Bt, C, N, lda, ldb, ldc, blockIdx.y * 128, blockIdx.x * 128, scale, K);
}

// ============== Flash pass A: on-the-fly QK^T -> per-row (m, 1/l) ==============
// Grid (16, NH), 512 threads (8 waves: 4 row-groups x 2 k-halves).
// Block = balanced strip pair (64*i rows and 1984-64*i), 33 k-tiles total.
// Per-lane deferred online (m,l) over the lane's fixed column subset; one
// cross-lane + LDS merge per strip.
__global__ __launch_bounds__(512) void fa_stats(const bf16* __restrict__ qpack,
                                                const bf16* __restrict__ kpack,
                                                float* __restrict__ stats) {
  const int h = blockIdx.y;
  const int g = h >> 2;
  __shared__ alignas(16) bf16 Qs[64 * 200];
  __shared__ alignas(16) bf16 Ks[64 * 200];
  __shared__ float2 sbuf[2][64];
  const int t = threadIdx.x;
  const int lane = t & 63;
  const int w = t >> 6;
  const int wm = (w & 3) * 16;     // row-group base within strip
  const int kh = w >> 2;           // k-half (0/1) of each 64-wide tile
  const int lr = lane & 15;
  const int lk = (lane >> 4) * 8;
  const bf16* Qg = qpack + (size_t)h * S * QKD;
  const bf16* Kg = kpack + (size_t)g * S * QKD;

  for (int sub = 0; sub < 2; ++sub) {
    const int m0 = sub ? (1984 - 64 * blockIdx.x) : (64 * blockIdx.x);
    const int ntiles = sub ? (32 - blockIdx.x) : (blockIdx.x + 1);
    __syncthreads();
    for (int c = t; c < 1536; c += 512) {
      int r = c / 24, cc = (c % 24) * 8;
      *reinterpret_cast<bf16x8*>(&Qs[r * 200 + cc]) =
          *reinterpret_cast<const bf16x8*>(&Qg[(size_t)(m0 + r) * QKD + cc]);
    }
    float mreg[4] = {-1e30f, -1e30f, -1e30f, -1e30f};
    float lreg[4] = {0.f, 0.f, 0.f, 0.f};

    for (int ti = 0; ti < ntiles; ++ti) {
      const int kt = ti * 64;
      lgkm_barrier();  // prev tile's LDS reads done
      for (int c = t; c < 1536; c += 512) {
        int r = c / 24, cc = (c % 24) * 8;
        *reinterpret_cast<bf16x8*>(&Ks[r * 200 + cc]) =
            *reinterpret_cast<const bf16x8*>(&Kg[(size_t)(kt + r) * QKD + cc]);
      }
      lgkm_barrier();  // Q + K visible
      f32x4 acc[2];
#pragma unroll
      for (int kb = 0; kb < 2; kb++) { f32x4 z = {0.f, 0.f, 0.f, 0.f}; acc[kb] = z; }
#pragma unroll
      for (int ks = 0; ks < 6; ++ks) {
        bf16x8 a = *reinterpret_cast<const bf16x8*>(&Qs[(wm + lr) * 200 + ks * 32 + lk]);
#pragma unroll
        for (int kb = 0; kb < 2; ++kb) {
          bf16x8 b = *reinterpret_cast<const bf16x8*>(&Ks[(kh * 32 + kb * 16 + lr) * 200 + ks * 32 + lk]);
          acc[kb] = __builtin_amdgcn_mfma_f32_16x16x32_bf16(a, b, acc[kb], 0, 0, 0);
        }
      }
      const int colb = kt + kh * 32 + lr;
#pragma unroll
      for (int q = 0; q < 4; ++q) {
        const int rowg = m0 + wm + (lane >> 4) * 4 + q;
        bool u0 = (colb <= rowg), u1 = (colb + 16 <= rowg);
        float s0 = u0 ? acc[0][q] * ATT_SCALE : -1e30f;
        float s1 = u1 ? acc[1][q] * ATT_SCALE : -1e30f;
        float nm = fmaxf(mreg[q], fmaxf(s0, s1));
        float e0 = u0 ? __expf(s0 - nm) : 0.f;
        float e1 = u1 ? __expf(s1 - nm) : 0.f;
        lreg[q] = lreg[q] * __expf(mreg[q] - nm) + e0 + e1;
        mreg[q] = nm;
      }
    }
    // cross-lane merge over lane bits 0-3 (cols)
#pragma unroll
    for (int q = 0; q < 4; ++q) {
      float m = mreg[q], l = lreg[q];
#pragma unroll
      for (int o = 1; o < 16; o <<= 1) {
        float mo = __shfl_xor(m, o, 64);
        float lo = __shfl_xor(l, o, 64);
        float M = fmaxf(m, mo);
        l = l * __expf(m - M) + lo * __expf(mo - M);
        m = M;
      }
      mreg[q] = m; lreg[q] = l;
    }
    __syncthreads();
    if ((lane & 15) == 0) {
#pragma unroll
      for (int q = 0; q < 4; ++q)
        sbuf[kh][wm + (lane >> 4) * 4 + q] = make_float2(mreg[q], lreg[q]);
    }
    __syncthreads();
    if (w < 4 && (lane & 15) == 0) {
#pragma unroll
      for (int q = 0; q < 4; ++q) {
        int r = wm + (lane >> 4) * 4 + q;
        float2 a = sbuf[0][r], b = sbuf[1][r];
        float M = fmaxf(a.x, b.x);
        float L = a.y * __expf(a.x - M) + b.y * __expf(b.x - M);
        stats[((size_t)h * S + m0 + r) * 2] = M;
        stats[((size_t)h * S + m0 + r) * 2 + 1] = 1.0f / L;
      }
    }
  }
}

// ============== Flash pass B: recompute QK^T, write normalized attn, PV =====
// Same grid/split as pass A. Per tile: stage K+V -> QK MFMA -> p=exp(s-m)/l
// (write fp32 attn, the only mandatory attn traffic; bf16 p -> Ps LDS) ->
// PV MFMA (A from Ps full-k, B from padded Vs; wave owns rows x d-half).
// Raw lgkm barriers: attn stores never drained.
__global__ __launch_bounds__(512) void fa_pv(const bf16* __restrict__ qpack,
                                             const bf16* __restrict__ kpack,
                                             const bf16* __restrict__ vt,
                                             const float* __restrict__ stats,
                                             float* __restrict__ attn,
                                             bf16* __restrict__ ctxb) {
  const int h = blockIdx.y;
  const int g = h >> 2;
  __shared__ alignas(16) bf16 Qs[64 * 200];
  __shared__ alignas(16) bf16 Ks[64 * 200];
  __shared__ alignas(16) bf16 Ps[64 * 72];
  __shared__ alignas(16) bf16 Vs[128 * 72];
  const int t = threadIdx.x;
  const int lane = t & 63;
  const int w = t >> 6;
  const int wm = (w & 3) * 16;     // row-group
  const int kh = w >> 2;           // k-half for QK, d-half for PV
  const int lr = lane & 15;
  const int lk = (lane >> 4) * 8;
  const bf16* Qg = qpack + (size_t)h * S * QKD;
  const bf16* Kg = kpack + (size_t)g * S * QKD;
  const bf16* Vg = vt + (size_t)g * HD * S;
  float* Ah = attn + (size_t)h * S * S;
  bf16* C = ctxb + h * HD;

  for (int sub = 0; sub < 2; ++sub) {
    const int m0 = sub ? (1984 - 64 * blockIdx.x) : (64 * blockIdx.x);
    const int ntiles = sub ? (32 - blockIdx.x) : (blockIdx.x + 1);
    const int kend = m0 + 64;
    __syncthreads();
    for (int c = t; c < 1536; c += 512) {
      int r = c / 24, cc = (c % 24) * 8;
      *reinterpret_cast<bf16x8*>(&Qs[r * 200 + cc]) =
          *reinterpret_cast<const bf16x8*>(&Qg[(size_t)(m0 + r) * QKD + cc]);
    }
    float mr[4], invl[4];
#pragma unroll
    for (int q = 0; q < 4; ++q) {
      const int rowg = m0 + wm + (lane >> 4) * 4 + q;
      mr[q] = stats[((size_t)h * S + rowg) * 2];
      invl[q] = stats[((size_t)h * S + rowg) * 2 + 1];
    }
    f32x4 accp[4];
#pragma unroll
    for (int j = 0; j < 4; j++) { f32x4 z = {0.f, 0.f, 0.f, 0.f}; accp[j] = z; }

    for (int ti = 0; ti < ntiles; ++ti) {
      const int kt = ti * 64;
      lgkm_barrier();  // prev tile's LDS reads done
      for (int c = t; c < 1536; c += 512) {
        int r = c / 24, cc = (c % 24) * 8;
        *reinterpret_cast<bf16x8*>(&Ks[r * 200 + cc]) =
            *reinterpret_cast<const bf16x8*>(&Kg[(size_t)(kt + r) * QKD + cc]);
      }
      for (int c = t; c < 1024; c += 512) {
        int r = c >> 3, cc = (c & 7) * 8;
        *reinterpret_cast<bf16x8*>(&Vs[r * 72 + cc]) =
            *reinterpret_cast<const bf16x8*>(&Vg[(size_t)r * S + kt + cc]);
      }
      lgkm_barrier();  // K, V (and Q) visible
      f32x4 acc[2];
#pragma unroll
      for (int kb = 0; kb < 2; kb++) { f32x4 z = {0.f, 0.f, 0.f, 0.f}; acc[kb] = z; }
#pragma unroll
      for (int ks = 0; ks < 6; ++ks) {
        bf16x8 a = *reinterpret_cast<const bf16x8*>(&Qs[(wm + lr) * 200 + ks * 32 + lk]);
#pragma unroll
        for (int kb = 0; kb < 2; ++kb) {
          bf16x8 b = *reinterpret_cast<const bf16x8*>(&Ks[(kh * 32 + kb * 16 + lr) * 200 + ks * 32 + lk]);
          acc[kb] = __builtin_amdgcn_mfma_f32_16x16x32_bf16(a, b, acc[kb], 0, 0, 0);
        }
      }
      const int colb = kt + kh * 32 + lr;
#pragma unroll
      for (int kb = 0; kb < 2; ++kb) {
#pragma unroll
        for (int q = 0; q < 4; ++q) {
          const int rloc = wm + (lane >> 4) * 4 + q;
          const int rowg = m0 + rloc;
          const int col = colb + kb * 16;
          float s = acc[kb][q] * ATT_SCALE;
          float p = (col <= rowg) ? __expf(s - mr[q]) * invl[q] : 0.f;
          Ah[(size_t)rowg * S + col] = p;
          Ps[rloc * 72 + kh * 32 + kb * 16 + lr] = (bf16)p;
        }
      }
      lgkm_barrier();  // Ps visible (all waves)
#pragma unroll
      for (int ks = 0; ks < 2; ++ks) {
        bf16x8 a = *reinterpret_cast<const bf16x8*>(&Ps[(wm + lr) * 72 + ks * 32 + lk]);
#pragma unroll
        for (int j = 0; j < 4; ++j) {
          bf16x8 b = *reinterpret_cast<const bf16x8*>(&Vs[(kh * 64 + j * 16 + lr) * 72 + ks * 32 + lk]);
          accp[j] = __builtin_amdgcn_mfma_f32_16x16x32_bf16(a, b, accp[j], 0, 0, 0);
        }
      }
    }

    // zero-fill causal tail [kend, S) for the strip's 64 rows
    const float4 zz = make_float4(0.f, 0.f, 0.f, 0.f);
    {
      const int zr = t >> 3, zc0 = (t & 7) * 4;
      float* zrow = Ah + (size_t)(m0 + zr) * S;
      for (int k = kend + zc0; k < S; k += 32) *reinterpret_cast<float4*>(zrow + k) = zz;
    }

    // ctx epilogue: wave's 16 rows x 64-d half
#pragma unroll
    for (int j = 0; j < 4; ++j) {
      const int d = kh * 64 + j * 16 + lr;
#pragma unroll
      for (int q = 0; q < 4; ++q) {
        const int rowg = m0 + wm + (lane >> 4) * 4 + q;
        C[(size_t)rowg * Hdim + d] = (bf16)accp[j][q];
      }
    }
  }
}

// ---------------- elementwise / reshape ----------------
__global__ __launch_bounds__(256) void cast_f32_bf16(const float* __restrict__ in,
                                                     bf16* __restrict__ out, int n8) {
  int i = blockIdx.x * 256 + threadIdx.x;
  if (i >= n8) return;
  float4 f0 = *reinterpret_cast<const float4*>(in + (size_t)i * 8);
  float4 f1 = *reinterpret_cast<const float4*>(in + (size_t)i * 8 + 4);
  bf16x8 v;
  v[0] = (bf16)f0.x; v[1] = (bf16)f0.y; v[2] = (bf16)f0.z; v[3] = (bf16)f0.w;
  v[4] = (bf16)f1.x; v[5] = (bf16)f1.y; v[6] = (bf16)f1.z; v[7] = (bf16)f1.w;
  *reinterpret_cast<bf16x8*>(out + (size_t)i * 8) = v;
}

// batched fp32 [R][C] -> bf16 [C][R] transposes (8 jobs, one dispatch)
struct TJobs {
  const float* src[8];
  bf16* dst[8];
  int R[8], C[8], tiles[8];
};

__global__ __launch_bounds__(256) void transpose_batch(TJobs J) {
  int tile = blockIdx.x;
  int j = 0;
  while (tile >= J.tiles[j]) { tile -= J.tiles[j]; ++j; }
  const int C = J.C[j], R = J.R[j];
  int tcn = C >> 5;
  int rb = (tile / tcn) * 32, cb = (tile % tcn) * 32;
  const float* in = J.src[j];
  bf16* out = J.dst[j];
  __shared__ float tl[32][33];
  int tx = threadIdx.x, ty = threadIdx.y;
#pragma unroll
  for (int q = 0; q < 32; q += 8)
    tl[ty + q][tx] = in[(size_t)(rb + ty + q) * C + cb + tx];
  __syncthreads();
#pragma unroll
  for (int q = 0; q < 32; q += 8)
    out[(size_t)(cb + ty + q) * R + rb + tx] = (bf16)tl[tx][ty + q];
}

// bf16 [R][C] (ld=ild) -> bf16 [C][R] (ld=old_)
__global__ __launch_bounds__(256) void transpose_b16(const bf16* __restrict__ in,
                                                     bf16* __restrict__ out, int R, int ild, int old_) {
  __shared__ float tl[32][33];
  int tx = threadIdx.x, ty = threadIdx.y;
  int cb = blockIdx.x * 32, rb = blockIdx.y * 32;
#pragma unroll
  for (int q = 0; q < 32; q += 8)
    tl[ty + q][tx] = (float)in[(size_t)(rb + ty + q) * ild + cb + tx];
  __syncthreads();
#pragma unroll
  for (int q = 0; q < 32; q += 8)
    out[(size_t)(cb + ty + q) * old_ + rb + tx] = (bf16)tl[tx][ty + q];
}

// fused RMSNorm for cq (y==0) and ckv (y==1) reading merged dproj
__global__ __launch_bounds__(256) void rmsnorm_fused(const float* __restrict__ dproj,
                                                     const float* __restrict__ qw,
                                                     const float* __restrict__ kw,
                                                     bf16* __restrict__ cqb,
                                                     bf16* __restrict__ ckvb) {
  int row = blockIdx.x;
  bool isq = (blockIdx.y == 0);
  int C = isq ? QC : KVC;
  const float* p = dproj + (size_t)row * DN + (isq ? 0 : QC);
  const float* w = isq ? qw : kw;
  bf16* out = (isq ? cqb : ckvb) + (size_t)row * C;
  float ss = 0.f;
  for (int i = threadIdx.x * 4; i < C; i += 1024) {
    float4 v = *reinterpret_cast<const float4*>(p + i);
    ss += v.x * v.x + v.y * v.y + v.z * v.z + v.w * v.w;
  }
  ss = block_sum(ss);
  float r = rsqrtf(ss / (float)C + RMS_EPS);
  for (int i = threadIdx.x * 4; i < C; i += 1024) {
    float4 v = *reinterpret_cast<const float4*>(p + i);
    float4 g = *reinterpret_cast<const float4*>(w + i);
    bf16x4 o;
    o[0] = (bf16)(v.x * r * g.x); o[1] = (bf16)(v.y * r * g.y);
    o[2] = (bf16)(v.z * r * g.z); o[3] = (bf16)(v.w * r * g.w);
    *reinterpret_cast<bf16x4*>(out + i) = o;
  }
}

// fused: pack qc slice of up1 into qpack + RoPE'd qr into qpack[...,128:]
__global__ __launch_bounds__(256) void build_qpack(const bf16* __restrict__ up1,
                                                   const float* __restrict__ cosp,
                                                   const float* __restrict__ sinp,
                                                   bf16* __restrict__ qpack) {
  int idx = blockIdx.x * 256 + threadIdx.x;
  const int P = NH * S * 16;  // 8-elem chunks of qc
  if (idx < P) {
    int d8 = idx & 15, s = (idx >> 4) & (S - 1), h = idx >> 15;
    int4 v = *reinterpret_cast<const int4*>(up1 + (size_t)s * 3072 + h * HD + d8 * 8);
    *reinterpret_cast<int4*>(qpack + ((size_t)h * S + s) * QKD + d8 * 8) = v;
  } else {
    int j = idx - P;
    int d0 = (j & 7) * 8, s = (j >> 3) & (S - 1), h = j >> 14;
    const bf16* xr = up1 + (size_t)s * 3072 + 2048 + h * RHD;
    bf16x8 xa = *reinterpret_cast<const bf16x8*>(xr + d0);
    bf16x8 xb = *reinterpret_cast<const bf16x8*>(xr + (d0 ^ 32));
    float sign = (d0 < 32) ? -1.f : 1.f;
    const float* cr = cosp + s * RHD + d0;
    const float* sr = sinp + s * RHD + d0;
    bf16x8 o;
#pragma unroll
    for (int i = 0; i < 8; i++)
      o[i] = (bf16)((float)xa[i] * cr[i] + sign * (float)xb[i] * sr[i]);
    *reinterpret_cast<bf16x8*>(qpack + ((size_t)h * S + s) * QKD + HD + d0) = o;
  }
}

// fused: pack kc slice of up2 into kpack + RoPE'd kr (from dproj col 2048) into all groups
__global__ __launch_bounds__(256) void build_kpack(const bf16* __restrict__ up2,
                                                   const float* __restrict__ dproj,
                                                   const float* __restrict__ cosp,
                                                   const float* __restrict__ sinp,
                                                   bf16* __restrict__ kpack) {
  int idx = blockIdx.x * 256 + threadIdx.x;
  const int P = NKV * S * 16;
  if (idx < P) {
    int d8 = idx & 15, s = (idx >> 4) & (S - 1), g = idx >> 15;
    int4 v = *reinterpret_cast<const int4*>(up2 + (size_t)s * 1024 + g * HD + d8 * 8);
    *reinterpret_cast<int4*>(kpack + ((size_t)g * S + s) * QKD + d8 * 8) = v;
  } else {
    int j = idx - P;
    int d0 = (j & 7) * 8, s = j >> 3;
    const float* xr = dproj + (size_t)s * DN + 2048;
    float4 a0 = *reinterpret_cast<const float4*>(xr + d0);
    float4 a1 = *reinterpret_cast<const float4*>(xr + d0 + 4);
    float4 b0 = *reinterpret_cast<const float4*>(xr + (d0 ^ 32));
    float4 b1 = *reinterpret_cast<const float4*>(xr + (d0 ^ 32) + 4);
    float sign = (d0 < 32) ? -1.f : 1.f;
    const float* cr = cosp + s * RHD + d0;
    const float* sr = sinp + s * RHD + d0;
    float xa[8] = {a0.x, a0.y, a0.z, a0.w, a1.x, a1.y, a1.z, a1.w};
    float xb[8] = {b0.x, b0.y, b0.z, b0.w, b1.x, b1.y, b1.z, b1.w};
    bf16x8 o;
#pragma unroll
    for (int i = 0; i < 8; i++)
      o[i] = (bf16)(xa[i] * cr[i] + sign * xb[i] * sr[i]);
#pragma unroll
    for (int g = 0; g < NKV; g++)
      *reinterpret_cast<bf16x8*>(kpack + ((size_t)g * S + s) * QKD + HD + d0) = o;
  }
}

// ---------------- launcher ----------------
extern "C" void kernel_launch(void* const* d_in, const int* in_sizes, int n_in, void* d_out,
                              int out_size, void* d_ws, size_t ws_size, hipStream_t stream) {
  const float* Xf = (const float*)d_in[0];
  const float* cosp = (const float*)d_in[1];
  const float* sinp = (const float*)d_in[2];
  const float* w_down_q = (const float*)d_in[4];
  const float* w_up_q = (const float*)d_in[5];
  const float* w_qr = (const float*)d_in[6];
  const float* w_down_kv = (const float*)d_in[7];
  const float* w_up_k = (const float*)d_in[8];
  const float* w_up_v = (const float*)d_in[9];
  const float* w_kr = (const float*)d_in[10];
  const float* w_o = (const float*)d_in[11];
  const float* q_norm_w = (const float*)d_in[12];
  const float* k_norm_w = (const float*)d_in[13];

  float* out0 = (float*)d_out;
  float* attn = out0 + (size_t)S * Hdim;

  char* base = (char*)d_ws;
  size_t off = 0;
  auto carve = [&](size_t bytes) -> void* {
    void* p = base + off;
    off += (bytes + 255) & ~(size_t)255;
    return p;
  };
  bf16* Xb      = (bf16*)carve((size_t)S * Hdim * 2);
  bf16* wt_down = (bf16*)carve((size_t)2176 * 2048 * 2);  // [2112(+pad)][2048]
  bf16* wt_up1  = (bf16*)carve((size_t)3072 * QC * 2);    // [3072][1536]
  bf16* wt_up2  = (bf16*)carve((size_t)1024 * KVC * 2);   // [1024][512]
  bf16* wt_o    = (bf16*)carve((size_t)Hdim * Hdim * 2);
  float* dproj  = (float*)carve((size_t)S * DN * 4);      // [2048][2112]
  bf16* cqb     = (bf16*)carve((size_t)S * QC * 2);
  bf16* ckvb    = (bf16*)carve((size_t)S * KVC * 2);
  bf16* up1     = (bf16*)carve((size_t)S * 3072 * 2);     // [s][qc 0:2048 | qr 2048:3072]
  bf16* up2     = (bf16*)carve((size_t)S * 1024 * 2);     // [s][kc 0:512 | v 512:1024]
  bf16* qpack   = (bf16*)carve((size_t)NH * S * QKD * 2);
  bf16* kpack   = (bf16*)carve((size_t)NKV * S * QKD * 2);
  bf16* vt      = (bf16*)carve((size_t)NKV * HD * S * 2);
  bf16* ctxb    = (bf16*)carve((size_t)S * Hdim * 2);
  float* stats  = (float*)carve((size_t)NH * S * 2 * 4);  // per-row (m, 1/l)
  (void)in_sizes; (void)n_in; (void)out_size; (void)ws_size;

  dim3 tb(32, 8);
  cast_f32_bf16<<<S * Hdim / 8 / 256, 256, 0, stream>>>(Xf, Xb, S * Hdim / 8);

  TJobs J;
  const float* srcs[8] = {w_down_q, w_down_kv, w_kr, w_up_q, w_qr, w_up_k, w_up_v, w_o};
  bf16* dsts[8] = {wt_down, wt_down + (size_t)QC * 2048, wt_down + (size_t)2048 * 2048,
                   wt_up1, wt_up1 + (size_t)2048 * QC, wt_up2, wt_up2 + (size_t)512 * KVC, wt_o};
  int Rs[8] = {2048, 2048, 2048, 1536, 1536, 512, 512, 2048};
  int Cs[8] = {1536, 512, 64, 2048, 1024, 512, 512, 2048};
  int total_tiles = 0;
  for (int j = 0; j < 8; j++) {
    J.src[j] = srcs[j]; J.dst[j] = dsts[j]; J.R[j] = Rs[j]; J.C[j] = Cs[j];
    J.tiles[j] = (Rs[j] / 32) * (Cs[j] / 32);
    total_tiles += J.tiles[j];
  }
  transpose_batch<<<total_tiles, tb, 0, stream>>>(J);

  // merged down projection: [S][2112] = Xb @ [wdq | wdkv | wkr]
  gemm_nt<float><<<dim3(17, 16), 256, 0, stream>>>(Xb, wt_down, dproj, DN, Hdim, Hdim, Hdim, DN, 1.f);
  rmsnorm_fused<<<dim3(S, 2), 256, 0, stream>>>(dproj, q_norm_w, k_norm_w, cqb, ckvb);

  // merged up projections
  gemm_nt<bf16><<<dim3(24, 16), 256, 0, stream>>>(cqb, wt_up1, up1, 3072, QC, QC, QC, 3072, 1.f);
  gemm_nt<bf16><<<dim3(8, 16), 256, 0, stream>>>(ckvb, wt_up2, up2, 1024, KVC, KVC, KVC, 1024, 1.f);

  build_qpack<<<(NH * S * 16 + NH * S * 8) / 256, 256, 0, stream>>>(up1, cosp, sinp, qpack);
  build_kpack<<<(NKV * S * 16 + S * 8) / 256, 256, 0, stream>>>(up2, dproj, cosp, sinp, kpack);
  transpose_b16<<<dim3(512 / 32, S / 32), tb, 0, stream>>>(up2 + 512, vt, S, 1024, S);

  // flash 2-pass: stats (recomputed QK^T) then normalized-attn + PV
  fa_stats<<<dim3(16, NH), 512, 0, stream>>>(qpack, kpack, stats);
  fa_pv<<<dim3(16, NH), 512, 0, stream>>>(qpack, kpack, vt, stats, attn, ctxb);

  // output projection
  gemm_nt<float><<<dim3(16, 16), 256, 0, stream>>>(ctxb, wt_o, out0, Hdim, Hdim, Hdim, Hdim, Hdim, 1.f);
}

// Round 10
// 370.655 us; speedup vs baseline: 1.1546x; 1.0682x over previous
//
#include <hip/hip_runtime.h>
#include <stdint.h>

typedef __bf16 bf16;
typedef __bf16 bf16x8 __attribute__((ext_vector_type(8)));
typedef __bf16 bf16x4 __attribute__((ext_vector_type(4)));
typedef float f32x4 __attribute__((ext_vector_type(4)));

#define DEVFN static __device__ __forceinline__

constexpr int S = 2048, Hdim = 2048, NH = 16, NKV = 4, HD = 128, RHD = 64, QC = 1536, KVC = 512;
constexpr int QKD = HD + RHD;                 // 192
constexpr int DN = 2112;                      // merged down-proj width: QC + KVC + RHD
constexpr float RMS_EPS = 1e-6f;
constexpr float ATT_SCALE = 0.07216878364870323f;  // 1/sqrt(192)

// ---------------- reductions ----------------
DEVFN float wave_sum(float v) {
#pragma unroll
  for (int o = 32; o > 0; o >>= 1) v += __shfl_xor(v, o, 64);
  return v;
}
DEVFN float block_sum(float v) {
  __shared__ float red_s[4];
  v = wave_sum(v);
  int lane = threadIdx.x & 63, wid = threadIdx.x >> 6;
  if (lane == 0) red_s[wid] = v;
  __syncthreads();
  v = red_s[0] + red_s[1] + red_s[2] + red_s[3];
  __syncthreads();
  return v;
}

DEVFN void lgkm_barrier() {
  asm volatile("s_waitcnt lgkmcnt(0)" ::: "memory");
  __builtin_amdgcn_s_barrier();
}

// ---------------- async global->LDS (16B per lane) ----------------
DEVFN void gload16(const bf16* g, bf16* l) {
  __builtin_amdgcn_global_load_lds(
      (const __attribute__((address_space(1))) uint32_t*)g,
      (__attribute__((address_space(3))) uint32_t*)l, 16, 0, 0);
}

// ---------------- async GEMM core (m97 structure): C = A[M,K] * Bt[N,K]^T ---
template <typename OT>
DEVFN void gemm_core_async(const bf16* __restrict__ A, const bf16* __restrict__ Bt,
                           OT* __restrict__ C, int N, int lda, int ldb, int ldc,
                           int m0, int n0, float scale, int kend) {
  __shared__ alignas(16) bf16 As[128 * 32];
  __shared__ alignas(16) bf16 Bs[128 * 32];
  const int t = threadIdx.x;
  const int lane = t & 63;
  const int wm = ((t >> 7) & 1) * 64;
  const int wn = ((t >> 6) & 1) * 64;
  const int lr = lane & 15;
  const int lk = (lane >> 4) * 8;
  const int srow = t >> 2;
  const int scol = (t & 3) * 8;
  const bf16* Ab = A + (size_t)(m0 + srow) * lda + scol;
  const bf16* Bb = Bt + (size_t)(n0 + srow) * ldb + scol;
  bf16* Al = As + t * 8;
  bf16* Bl = Bs + t * 8;

  f32x4 acc[4][4];
#pragma unroll
  for (int i = 0; i < 4; i++)
#pragma unroll
    for (int j = 0; j < 4; j++) { f32x4 z = {0.f, 0.f, 0.f, 0.f}; acc[i][j] = z; }

  for (int kk = 0; kk < kend; kk += 32) {
    gload16(Ab + kk, Al);
    gload16(Ab + (size_t)64 * lda + kk, Al + 2048);
    gload16(Bb + kk, Bl);
    gload16(Bb + (size_t)64 * ldb + kk, Bl + 2048);
    __syncthreads();
    bf16x8 a[4], b[4];
#pragma unroll
    for (int i = 0; i < 4; i++)
      a[i] = *reinterpret_cast<const bf16x8*>(&As[(wm + i * 16 + lr) * 32 + lk]);
#pragma unroll
    for (int i = 0; i < 4; i++)
      b[i] = *reinterpret_cast<const bf16x8*>(&Bs[(wn + i * 16 + lr) * 32 + lk]);
#pragma unroll
    for (int i = 0; i < 4; i++)
#pragma unroll
      for (int j = 0; j < 4; j++)
        acc[i][j] = __builtin_amdgcn_mfma_f32_16x16x32_bf16(a[i], b[j], acc[i][j], 0, 0, 0);
    __syncthreads();
  }
  const int orow = (lane >> 4) * 4;
#pragma unroll
  for (int i = 0; i < 4; i++) {
#pragma unroll
    for (int j = 0; j < 4; j++) {
      int col = n0 + wn + j * 16 + lr;
      if (col < N) {
#pragma unroll
        for (int q = 0; q < 4; q++) {
          int row = m0 + wm + i * 16 + orow + q;
          C[(size_t)row * ldc + col] = (OT)(acc[i][j][q] * scale);
        }
      }
    }
  }
}

template <typename OT>
__global__ __launch_bounds__(256) void gemm_nt(const bf16* __restrict__ A, const bf16* __restrict__ Bt,
                                               OT* __restrict__ C, int N, int K, int lda,
                                               int ldb, int ldc, float scale) {
  gemm_core_async<OT>(A, Bt, C, N, lda, ldb, ldc, blockIdx.y * 128, blockIdx.x * 128, scale, K);
}

// up1 (384 blocks) + up2 (128 blocks) in one launch
__global__ __launch_bounds__(256) void gemm_up_both(const bf16* __restrict__ cqb,
                                                    const bf16* __restrict__ ckvb,
                                                    const bf16* __restrict__ wt_up1,
                                                    const bf16* __restrict__ wt_up2,
                                                    bf16* __restrict__ up1,
                                                    bf16* __restrict__ up2) {
  int id = blockIdx.x;
  if (id < 384) {
    gemm_core_async<bf16>(cqb, wt_up1, up1, 3072, QC, QC, 3072, (id / 24) * 128, (id % 24) * 128, 1.f, QC);
  } else {
    id -= 384;
    gemm_core_async<bf16>(ckvb, wt_up2, up2, 1024, KVC, KVC, 1024, (id / 8) * 128, (id % 8) * 128, 1.f, KVC);
  }
}

// ============== Fused flash attention: stats loop + normalize/write/PV loop ==
// Grid (16, NH), 512 threads (8 waves: 4 row-groups x 2 k-halves).
// Block = balanced strip pair (64*i rows and 1984-64*i), 33 k-tiles total.
// Loop 1: on-the-fly QK^T -> per-lane deferred online (m,l) -> strip stats in
// LDS (aliased into Ps). Loop 2: recompute QK^T, p=exp(s-m)/l, write fp32 attn
// (the only mandatory attn traffic), bf16 p -> Ps, PV MFMA. Raw lgkm barriers:
// attn stores never drained.
__global__ __launch_bounds__(512) void fa_fused(const bf16* __restrict__ qpack,
                                                const bf16* __restrict__ kpack,
                                                const bf16* __restrict__ vt,
                                                float* __restrict__ attn,
                                                bf16* __restrict__ ctxb) {
  const int h = blockIdx.y;
  const int g = h >> 2;
  __shared__ alignas(16) bf16 Qs[64 * 200];
  __shared__ alignas(16) bf16 Ks[64 * 200];
  __shared__ alignas(16) bf16 Ps[64 * 72];
  __shared__ alignas(16) bf16 Vs[128 * 72];
  // stats scratch aliased into Ps (Ps unused during loop 1; stats are read
  // into registers before loop 2 overwrites Ps)
  float2* sb = reinterpret_cast<float2*>(Ps);      // sb[0..127]: per-half merge
  float2* statf = sb + 128;                        // statf[0..63]: final (m, 1/l)

  const int t = threadIdx.x;
  const int lane = t & 63;
  const int w = t >> 6;
  const int wm = (w & 3) * 16;     // row-group base within strip
  const int kh = w >> 2;           // k-half (QK) / d-half (PV)
  const int lr = lane & 15;
  const int lk = (lane >> 4) * 8;
  const bf16* Qg = qpack + (size_t)h * S * QKD;
  const bf16* Kg = kpack + (size_t)g * S * QKD;
  const bf16* Vg = vt + (size_t)g * HD * S;
  float* Ah = attn + (size_t)h * S * S;
  bf16* C = ctxb + h * HD;

  for (int sub = 0; sub < 2; ++sub) {
    const int m0 = sub ? (1984 - 64 * blockIdx.x) : (64 * blockIdx.x);
    const int ntiles = sub ? (32 - blockIdx.x) : (blockIdx.x + 1);
    const int kend = m0 + 64;
    __syncthreads();
    for (int c = t; c < 1536; c += 512) {
      int r = c / 24, cc = (c % 24) * 8;
      *reinterpret_cast<bf16x8*>(&Qs[r * 200 + cc]) =
          *reinterpret_cast<const bf16x8*>(&Qg[(size_t)(m0 + r) * QKD + cc]);
    }

    // ---------- loop 1: stats ----------
    float mreg[4] = {-1e30f, -1e30f, -1e30f, -1e30f};
    float lreg[4] = {0.f, 0.f, 0.f, 0.f};
    for (int ti = 0; ti < ntiles; ++ti) {
      const int kt = ti * 64;
      lgkm_barrier();  // prev tile's LDS reads done (and Qs staged at ti=0)
      for (int c = t; c < 1536; c += 512) {
        int r = c / 24, cc = (c % 24) * 8;
        *reinterpret_cast<bf16x8*>(&Ks[r * 200 + cc]) =
            *reinterpret_cast<const bf16x8*>(&Kg[(size_t)(kt + r) * QKD + cc]);
      }
      lgkm_barrier();  // Q + K visible
      f32x4 acc[2];
#pragma unroll
      for (int kb = 0; kb < 2; kb++) { f32x4 z = {0.f, 0.f, 0.f, 0.f}; acc[kb] = z; }
#pragma unroll
      for (int ks = 0; ks < 6; ++ks) {
        bf16x8 a = *reinterpret_cast<const bf16x8*>(&Qs[(wm + lr) * 200 + ks * 32 + lk]);
#pragma unroll
        for (int kb = 0; kb < 2; ++kb) {
          bf16x8 b = *reinterpret_cast<const bf16x8*>(&Ks[(kh * 32 + kb * 16 + lr) * 200 + ks * 32 + lk]);
          acc[kb] = __builtin_amdgcn_mfma_f32_16x16x32_bf16(a, b, acc[kb], 0, 0, 0);
        }
      }
      const int colb = kt + kh * 32 + lr;
#pragma unroll
      for (int q = 0; q < 4; ++q) {
        const int rowg = m0 + wm + (lane >> 4) * 4 + q;
        bool u0 = (colb <= rowg), u1 = (colb + 16 <= rowg);
        float s0 = u0 ? acc[0][q] * ATT_SCALE : -1e30f;
        float s1 = u1 ? acc[1][q] * ATT_SCALE : -1e30f;
        float nm = fmaxf(mreg[q], fmaxf(s0, s1));
        float e0 = u0 ? __expf(s0 - nm) : 0.f;
        float e1 = u1 ? __expf(s1 - nm) : 0.f;
        lreg[q] = lreg[q] * __expf(mreg[q] - nm) + e0 + e1;
        mreg[q] = nm;
      }
    }
    // cross-lane merge over lane bits 0-3 (cols)
#pragma unroll
    for (int q = 0; q < 4; ++q) {
      float m = mreg[q], l = lreg[q];
#pragma unroll
      for (int o = 1; o < 16; o <<= 1) {
        float mo = __shfl_xor(m, o, 64);
        float lo = __shfl_xor(l, o, 64);
        float M = fmaxf(m, mo);
        l = l * __expf(m - M) + lo * __expf(mo - M);
        m = M;
      }
      mreg[q] = m; lreg[q] = l;
    }
    __syncthreads();  // Ks reads of last tile done; Ps alias safe to write
    if ((lane & 15) == 0) {
#pragma unroll
      for (int q = 0; q < 4; ++q)
        sb[kh * 64 + wm + (lane >> 4) * 4 + q] = make_float2(mreg[q], lreg[q]);
    }
    __syncthreads();
    if (w < 4 && (lane & 15) == 0) {
#pragma unroll
      for (int q = 0; q < 4; ++q) {
        int r = wm + (lane >> 4) * 4 + q;
        float2 a = sb[r], b = sb[64 + r];
        float M = fmaxf(a.x, b.x);
        float L = a.y * __expf(a.x - M) + b.y * __expf(b.x - M);
        statf[r] = make_float2(M, 1.0f / L);
      }
    }
    __syncthreads();
    float mr[4], invl[4];
#pragma unroll
    for (int q = 0; q < 4; ++q) {
      float2 sv = statf[wm + (lane >> 4) * 4 + q];
      mr[q] = sv.x; invl[q] = sv.y;
    }
    __syncthreads();  // all stats read to regs; Ps free for loop 2

    // ---------- loop 2: normalize + attn write + PV ----------
    f32x4 accp[4];
#pragma unroll
    for (int j = 0; j < 4; j++) { f32x4 z = {0.f, 0.f, 0.f, 0.f}; accp[j] = z; }

    for (int ti = 0; ti < ntiles; ++ti) {
      const int kt = ti * 64;
      lgkm_barrier();  // prev tile's LDS reads done
      for (int c = t; c < 1536; c += 512) {
        int r = c / 24, cc = (c % 24) * 8;
        *reinterpret_cast<bf16x8*>(&Ks[r * 200 + cc]) =
            *reinterpret_cast<const bf16x8*>(&Kg[(size_t)(kt + r) * QKD + cc]);
      }
      for (int c = t; c < 1024; c += 512) {
        int r = c >> 3, cc = (c & 7) * 8;
        *reinterpret_cast<bf16x8*>(&Vs[r * 72 + cc]) =
            *reinterpret_cast<const bf16x8*>(&Vg[(size_t)r * S + kt + cc]);
      }
      lgkm_barrier();  // K, V (and Q) visible
      f32x4 acc[2];
#pragma unroll
      for (int kb = 0; kb < 2; kb++) { f32x4 z = {0.f, 0.f, 0.f, 0.f}; acc[kb] = z; }
#pragma unroll
      for (int ks = 0; ks < 6; ++ks) {
        bf16x8 a = *reinterpret_cast<const bf16x8*>(&Qs[(wm + lr) * 200 + ks * 32 + lk]);
#pragma unroll
        for (int kb = 0; kb < 2; ++kb) {
          bf16x8 b = *reinterpret_cast<const bf16x8*>(&Ks[(kh * 32 + kb * 16 + lr) * 200 + ks * 32 + lk]);
          acc[kb] = __builtin_amdgcn_mfma_f32_16x16x32_bf16(a, b, acc[kb], 0, 0, 0);
        }
      }
      const int colb = kt + kh * 32 + lr;
#pragma unroll
      for (int kb = 0; kb < 2; ++kb) {
#pragma unroll
        for (int q = 0; q < 4; ++q) {
          const int rloc = wm + (lane >> 4) * 4 + q;
          const int rowg = m0 + rloc;
          const int col = colb + kb * 16;
          float s = acc[kb][q] * ATT_SCALE;
          float p = (col <= rowg) ? __expf(s - mr[q]) * invl[q] : 0.f;
          Ah[(size_t)rowg * S + col] = p;
          Ps[rloc * 72 + kh * 32 + kb * 16 + lr] = (bf16)p;
        }
      }
      lgkm_barrier();  // Ps visible (all waves)
#pragma unroll
      for (int ks = 0; ks < 2; ++ks) {
        bf16x8 a = *reinterpret_cast<const bf16x8*>(&Ps[(wm + lr) * 72 + ks * 32 + lk]);
#pragma unroll
        for (int j = 0; j < 4; ++j) {
          bf16x8 b = *reinterpret_cast<const bf16x8*>(&Vs[(kh * 64 + j * 16 + lr) * 72 + ks * 32 + lk]);
          accp[j] = __builtin_amdgcn_mfma_f32_16x16x32_bf16(a, b, accp[j], 0, 0, 0);
        }
      }
    }

    // zero-fill causal tail [kend, S) for the strip's 64 rows
    const float4 zz = make_float4(0.f, 0.f, 0.f, 0.f);
    {
      const int zr = t >> 3, zc0 = (t & 7) * 4;
      float* zrow = Ah + (size_t)(m0 + zr) * S;
      for (int k = kend + zc0; k < S; k += 32) *reinterpret_cast<float4*>(zrow + k) = zz;
    }

    // ctx epilogue: wave's 16 rows x 64-d half
#pragma unroll
    for (int j = 0; j < 4; ++j) {
      const int d = kh * 64 + j * 16 + lr;
#pragma unroll
      for (int q = 0; q < 4; ++q) {
        const int rowg = m0 + wm + (lane >> 4) * 4 + q;
        C[(size_t)rowg * Hdim + d] = (bf16)accp[j][q];
      }
    }
  }
}

// ---------------- fused prep: X cast + 8 weight transposes ----------------
struct TJobs {
  const float* src[8];
  bf16* dst[8];
  int R[8], C[8], tiles[8];
};

__global__ __launch_bounds__(256) void prep(const float* __restrict__ Xf,
                                            bf16* __restrict__ Xb, TJobs J) {
  const int t = threadIdx.x;
  int id = blockIdx.x;
  if (id < 2048) {  // cast: 2048 blocks x 256 threads x 8 elems = S*Hdim
    size_t i = (size_t)id * 256 + t;
    float4 f0 = *reinterpret_cast<const float4*>(Xf + i * 8);
    float4 f1 = *reinterpret_cast<const float4*>(Xf + i * 8 + 4);
    bf16x8 v;
    v[0] = (bf16)f0.x; v[1] = (bf16)f0.y; v[2] = (bf16)f0.z; v[3] = (bf16)f0.w;
    v[4] = (bf16)f1.x; v[5] = (bf16)f1.y; v[6] = (bf16)f1.z; v[7] = (bf16)f1.w;
    *reinterpret_cast<bf16x8*>(Xb + i * 8) = v;
    return;
  }
  int tile = id - 2048;
  int j = 0;
  while (tile >= J.tiles[j]) { tile -= J.tiles[j]; ++j; }
  const int C = J.C[j], R = J.R[j];
  int tcn = C >> 5;
  int rb = (tile / tcn) * 32, cb = (tile % tcn) * 32;
  const float* in = J.src[j];
  bf16* out = J.dst[j];
  __shared__ float tl[32][33];
  int tx = t & 31, ty = t >> 5;
#pragma unroll
  for (int q = 0; q < 32; q += 8)
    tl[ty + q][tx] = in[(size_t)(rb + ty + q) * C + cb + tx];
  __syncthreads();
#pragma unroll
  for (int q = 0; q < 32; q += 8)
    out[(size_t)(cb + ty + q) * R + rb + tx] = (bf16)tl[tx][ty + q];
}

// fused RMSNorm for cq (y==0) and ckv (y==1) reading merged dproj
__global__ __launch_bounds__(256) void rmsnorm_fused(const float* __restrict__ dproj,
                                                     const float* __restrict__ qw,
                                                     const float* __restrict__ kw,
                                                     bf16* __restrict__ cqb,
                                                     bf16* __restrict__ ckvb) {
  int row = blockIdx.x;
  bool isq = (blockIdx.y == 0);
  int C = isq ? QC : KVC;
  const float* p = dproj + (size_t)row * DN + (isq ? 0 : QC);
  const float* w = isq ? qw : kw;
  bf16* out = (isq ? cqb : ckvb) + (size_t)row * C;
  float ss = 0.f;
  for (int i = threadIdx.x * 4; i < C; i += 1024) {
    float4 v = *reinterpret_cast<const float4*>(p + i);
    ss += v.x * v.x + v.y * v.y + v.z * v.z + v.w * v.w;
  }
  ss = block_sum(ss);
  float r = rsqrtf(ss / (float)C + RMS_EPS);
  for (int i = threadIdx.x * 4; i < C; i += 1024) {
    float4 v = *reinterpret_cast<const float4*>(p + i);
    float4 g = *reinterpret_cast<const float4*>(w + i);
    bf16x4 o;
    o[0] = (bf16)(v.x * r * g.x); o[1] = (bf16)(v.y * r * g.y);
    o[2] = (bf16)(v.z * r * g.z); o[3] = (bf16)(v.w * r * g.w);
    *reinterpret_cast<bf16x4*>(out + i) = o;
  }
}

// ---------------- fused pack: qpack + kpack + V transpose ----------------
// blocks [0,3072): build_qpack; [3072,3648): build_kpack; [3648,4672): vt
__global__ __launch_bounds__(256) void pack_all(const bf16* __restrict__ up1,
                                                const bf16* __restrict__ up2,
                                                const float* __restrict__ dproj,
                                                const float* __restrict__ cosp,
                                                const float* __restrict__ sinp,
                                                bf16* __restrict__ qpack,
                                                bf16* __restrict__ kpack,
                                                bf16* __restrict__ vt) {
  const int t = threadIdx.x;
  int id = blockIdx.x;
  if (id < 3072) {  // ---- qpack ----
    int idx = id * 256 + t;
    const int P = NH * S * 16;
    if (idx < P) {
      int d8 = idx & 15, s = (idx >> 4) & (S - 1), h = idx >> 15;
      int4 v = *reinterpret_cast<const int4*>(up1 + (size_t)s * 3072 + h * HD + d8 * 8);
      *reinterpret_cast<int4*>(qpack + ((size_t)h * S + s) * QKD + d8 * 8) = v;
    } else {
      int j = idx - P;
      int d0 = (j & 7) * 8, s = (j >> 3) & (S - 1), h = j >> 14;
      const bf16* xr = up1 + (size_t)s * 3072 + 2048 + h * RHD;
      bf16x8 xa = *reinterpret_cast<const bf16x8*>(xr + d0);
      bf16x8 xb = *reinterpret_cast<const bf16x8*>(xr + (d0 ^ 32));
      float sign = (d0 < 32) ? -1.f : 1.f;
      const float* cr = cosp + s * RHD + d0;
      const float* sr = sinp + s * RHD + d0;
      bf16x8 o;
#pragma unroll
      for (int i = 0; i < 8; i++)
        o[i] = (bf16)((float)xa[i] * cr[i] + sign * (float)xb[i] * sr[i]);
      *reinterpret_cast<bf16x8*>(qpack + ((size_t)h * S + s) * QKD + HD + d0) = o;
    }
    return;
  }
  if (id < 3648) {  // ---- kpack ----
    int idx = (id - 3072) * 256 + t;
    const int P = NKV * S * 16;
    if (idx < P) {
      int d8 = idx & 15, s = (idx >> 4) & (S - 1), g = idx >> 15;
      int4 v = *reinterpret_cast<const int4*>(up2 + (size_t)s * 1024 + g * HD + d8 * 8);
      *reinterpret_cast<int4*>(kpack + ((size_t)g * S + s) * QKD + d8 * 8) = v;
    } else {
      int j = idx - P;
      int d0 = (j & 7) * 8, s = j >> 3;
      const float* xr = dproj + (size_t)s * DN + 2048;
      float4 a0 = *reinterpret_cast<const float4*>(xr + d0);
      float4 a1 = *reinterpret_cast<const float4*>(xr + d0 + 4);
      float4 b0 = *reinterpret_cast<const float4*>(xr + (d0 ^ 32));
      float4 b1 = *reinterpret_cast<const float4*>(xr + (d0 ^ 32) + 4);
      float sign = (d0 < 32) ? -1.f : 1.f;
      const float* cr = cosp + s * RHD + d0;
      const float* sr = sinp + s * RHD + d0;
      float xa[8] = {a0.x, a0.y, a0.z, a0.w, a1.x, a1.y, a1.z, a1.w};
      float xb[8] = {b0.x, b0.y, b0.z, b0.w, b1.x, b1.y, b1.z, b1.w};
      bf16x8 o;
#pragma unroll
      for (int i = 0; i < 8; i++)
        o[i] = (bf16)(xa[i] * cr[i] + sign * xb[i] * sr[i]);
#pragma unroll
      for (int g = 0; g < NKV; g++)
        *reinterpret_cast<bf16x8*>(kpack + ((size_t)g * S + s) * QKD + HD + d0) = o;
    }
    return;
  }
  // ---- V transpose: up2[s][512+c] -> vt[c][s], tiles 16 x 64 ----
  int tile = id - 3648;
  int cb = (tile & 15) * 32;   // source col block (0..511)
  int rb = (tile >> 4) * 32;   // source row block (0..2047)
  __shared__ float tl[32][33];
  int tx = t & 31, ty = t >> 5;
  const bf16* in = up2 + 512;
#pragma unroll
  for (int q = 0; q < 32; q += 8)
    tl[ty + q][tx] = (float)in[(size_t)(rb + ty + q) * 1024 + cb + tx];
  __syncthreads();
#pragma unroll
  for (int q = 0; q < 32; q += 8)
    vt[(size_t)(cb + ty + q) * S + rb + tx] = (bf16)tl[tx][ty + q];
}

// ---------------- launcher ----------------
extern "C" void kernel_launch(void* const* d_in, const int* in_sizes, int n_in, void* d_out,
                              int out_size, void* d_ws, size_t ws_size, hipStream_t stream) {
  const float* Xf = (const float*)d_in[0];
  const float* cosp = (const float*)d_in[1];
  const float* sinp = (const float*)d_in[2];
  const float* w_down_q = (const float*)d_in[4];
  const float* w_up_q = (const float*)d_in[5];
  const float* w_qr = (const float*)d_in[6];
  const float* w_down_kv = (const float*)d_in[7];
  const float* w_up_k = (const float*)d_in[8];
  const float* w_up_v = (const float*)d_in[9];
  const float* w_kr = (const float*)d_in[10];
  const float* w_o = (const float*)d_in[11];
  const float* q_norm_w = (const float*)d_in[12];
  const float* k_norm_w = (const float*)d_in[13];

  float* out0 = (float*)d_out;
  float* attn = out0 + (size_t)S * Hdim;

  char* base = (char*)d_ws;
  size_t off = 0;
  auto carve = [&](size_t bytes) -> void* {
    void* p = base + off;
    off += (bytes + 255) & ~(size_t)255;
    return p;
  };
  bf16* Xb      = (bf16*)carve((size_t)S * Hdim * 2);
  bf16* wt_down = (bf16*)carve((size_t)2176 * 2048 * 2);  // [2112(+pad)][2048]
  bf16* wt_up1  = (bf16*)carve((size_t)3072 * QC * 2);    // [3072][1536]
  bf16* wt_up2  = (bf16*)carve((size_t)1024 * KVC * 2);   // [1024][512]
  bf16* wt_o    = (bf16*)carve((size_t)Hdim * Hdim * 2);
  float* dproj  = (float*)carve((size_t)S * DN * 4);      // [2048][2112]
  bf16* cqb     = (bf16*)carve((size_t)S * QC * 2);
  bf16* ckvb    = (bf16*)carve((size_t)S * KVC * 2);
  bf16* up1     = (bf16*)carve((size_t)S * 3072 * 2);     // [s][qc 0:2048 | qr 2048:3072]
  bf16* up2     = (bf16*)carve((size_t)S * 1024 * 2);     // [s][kc 0:512 | v 512:1024]
  bf16* qpack   = (bf16*)carve((size_t)NH * S * QKD * 2);
  bf16* kpack   = (bf16*)carve((size_t)NKV * S * QKD * 2);
  bf16* vt      = (bf16*)carve((size_t)NKV * HD * S * 2);
  bf16* ctxb    = (bf16*)carve((size_t)S * Hdim * 2);
  (void)in_sizes; (void)n_in; (void)out_size; (void)ws_size;

  TJobs J;
  const float* srcs[8] = {w_down_q, w_down_kv, w_kr, w_up_q, w_qr, w_up_k, w_up_v, w_o};
  bf16* dsts[8] = {wt_down, wt_down + (size_t)QC * 2048, wt_down + (size_t)2048 * 2048,
                   wt_up1, wt_up1 + (size_t)2048 * QC, wt_up2, wt_up2 + (size_t)512 * KVC, wt_o};
  int Rs[8] = {2048, 2048, 2048, 1536, 1536, 512, 512, 2048};
  int Cs[8] = {1536, 512, 64, 2048, 1024, 512, 512, 2048};
  int total_tiles = 0;
  for (int j = 0; j < 8; j++) {
    J.src[j] = srcs[j]; J.dst[j] = dsts[j]; J.R[j] = Rs[j]; J.C[j] = Cs[j];
    J.tiles[j] = (Rs[j] / 32) * (Cs[j] / 32);
    total_tiles += J.tiles[j];
  }

  // 1. prep: X cast + all weight transposes
  prep<<<2048 + total_tiles, 256, 0, stream>>>(Xf, Xb, J);
  // 2. merged down projection: [S][2112] = Xb @ [wdq | wdkv | wkr]
  gemm_nt<float><<<dim3(17, 16), 256, 0, stream>>>(Xb, wt_down, dproj, DN, Hdim, Hdim, Hdim, DN, 1.f);
  // 3. both RMSNorms
  rmsnorm_fused<<<dim3(S, 2), 256, 0, stream>>>(dproj, q_norm_w, k_norm_w, cqb, ckvb);
  // 4. both up projections
  gemm_up_both<<<512, 256, 0, stream>>>(cqb, ckvb, wt_up1, wt_up2, up1, up2);
  // 5. pack q/k + RoPE + V transpose
  pack_all<<<4672, 256, 0, stream>>>(up1, up2, dproj, cosp, sinp, qpack, kpack, vt);
  // 6. fused flash attention (stats + normalized-attn + PV)
  fa_fused<<<dim3(16, NH), 512, 0, stream>>>(qpack, kpack, vt, attn, ctxb);
  // 7. output projection
  gemm_nt<float><<<dim3(16, 16), 256, 0, stream>>>(ctxb, wt_o, out0, Hdim, Hdim, Hdim, Hdim, Hdim, 1.f);
}